// Round 1
// baseline (2845.387 us; speedup 1.0000x reference)
//
#include <hip/hip_runtime.h>
#include <math.h>

#define B_ 8
#define T_ 8192
#define V_ 256
#define EB_ 64
#define E_ 64
#define H_ 512
#define SS_ 32
#define FEAT_ 132
#define NCH_ 256   // T/CHUNK
#define CHUNK_ 32

__device__ __forceinline__ float silu_f(float x) { return x / (1.0f + expf(-x)); }
__device__ __forceinline__ float sigm_f(float x) { return 1.0f / (1.0f + expf(-x)); }

__device__ __forceinline__ float blockReduce256(float v, volatile float* red) {
#pragma unroll
    for (int off = 32; off; off >>= 1) v += __shfl_xor(v, off, 64);
    int wid = threadIdx.x >> 6;
    if ((threadIdx.x & 63) == 0) red[wid] = v;
    __syncthreads();
    float t = red[0] + red[1] + red[2] + red[3];
    __syncthreads();
    return t;
}

// ---------------- K1: token features (byte emb, hashes, scale attn, match feats)
__global__ __launch_bounds__(256) void k_token_feats(
    const int* __restrict__ chars, const float* __restrict__ emb_byte,
    const float* __restrict__ hash_tables, const float* __restrict__ Wq,
    const float* __restrict__ bq, float* __restrict__ feat, float* __restrict__ hfpre) {
    int wave = threadIdx.x >> 6, lane = threadIdx.x & 63;
    int token = blockIdx.x * 4 + wave;
    int t = token & (T_ - 1);
    int b = token >> 13;
    const int* crow = chars + b * T_;
    int cj = 0;
    if (lane < 16 && (t - lane) >= 0) cj = crow[t - lane];
    int cv[16];
#pragma unroll
    for (int j = 0; j < 16; j++) cv[j] = __shfl(cj, j, 64);
    // rolling hashes: p_j = (1+256j) mod 4096
    int acc = 0;
    int hidx[4];
#pragma unroll
    for (int j = 0; j < 16; j++) {
        acc += cv[j] * (1 + 256 * j);
        if (j == 1) hidx[0] = acc & 4095;
        if (j == 3) hidx[1] = acc & 4095;
        if (j == 7) hidx[2] = acc & 4095;
        if (j == 15) hidx[3] = acc & 4095;
    }
    float be = emb_byte[cv[0] * EB_ + lane];
    float se[4];
#pragma unroll
    for (int s = 0; s < 4; s++) se[s] = hash_tables[(s * 4096 + hidx[s]) * E_ + lane];
    // q = byte_emb @ Wq + bq
    float q = bq[lane];
#pragma unroll
    for (int k = 0; k < 64; k++) q += __shfl(be, k, 64) * Wq[k * 64 + lane];
    // scores + softmax over 4 scales
    float sc[4];
#pragma unroll
    for (int s = 0; s < 4; s++) {
        float v = q * se[s];
#pragma unroll
        for (int off = 32; off; off >>= 1) v += __shfl_xor(v, off, 64);
        sc[s] = v * 0.125f;
    }
    float mx = fmaxf(fmaxf(sc[0], sc[1]), fmaxf(sc[2], sc[3]));
    float w0 = expf(sc[0] - mx), w1 = expf(sc[1] - mx), w2 = expf(sc[2] - mx), w3 = expf(sc[3] - mx);
    float inv = 1.0f / (w0 + w1 + w2 + w3);
    float hf = (w0 * se[0] + w1 * se[1] + w2 * se[2] + w3 * se[3]) * inv;
    feat[token * FEAT_ + lane] = be;
    hfpre[token * E_ + lane] = hf;
    if (lane < 4) {
        int k = 1 << lane;
        float m = (t >= k && cv[0] == cv[k]) ? 1.0f : 0.0f;
        feat[token * FEAT_ + 128 + lane] = m;
    }
}

// ---------------- K2: causal depthwise conv(4) + silu -> feat[64:128]
__global__ __launch_bounds__(256) void k_conv(
    const float* __restrict__ hfpre, const float* __restrict__ conv_w,
    const float* __restrict__ conv_b, float* __restrict__ feat) {
    int idx = blockIdx.x * 256 + threadIdx.x;   // B*T*E
    int e = idx & 63;
    int bt = idx >> 6;
    int t = bt & (T_ - 1);
    float acc = conv_b[e];
#pragma unroll
    for (int k = 0; k < 4; k++) {
        int tt = t - 3 + k;
        if (tt >= 0) acc += hfpre[(bt - 3 + k) * E_ + e] * conv_w[e * 4 + k];
    }
    feat[bt * FEAT_ + 64 + e] = silu_f(acc);
}

// ---------------- K3: h = silu(feat @ Win + b_in), 16 tokens/block
__global__ __launch_bounds__(256) void k_win(
    const float* __restrict__ feat, const float* __restrict__ Win,
    const float* __restrict__ b_in, float* __restrict__ h) {
    __shared__ float sf[16 * FEAT_];
    int bt0 = blockIdx.x * 16;
    {
        const float4* src = (const float4*)(feat + bt0 * FEAT_);
        float4* dst = (float4*)sf;
        for (int i = threadIdx.x; i < 16 * FEAT_ / 4; i += 256) dst[i] = src[i];
    }
    __syncthreads();
    int n0 = threadIdx.x, n1 = threadIdx.x + 256;
    float acc0[16] = {}, acc1[16] = {};
    for (int k = 0; k < FEAT_; k += 4) {
        float w0[4], w1[4];
#pragma unroll
        for (int kk = 0; kk < 4; kk++) {
            w0[kk] = Win[(k + kk) * H_ + n0];
            w1[kk] = Win[(k + kk) * H_ + n1];
        }
#pragma unroll
        for (int m = 0; m < 16; m++) {
            float4 a = *(const float4*)&sf[m * FEAT_ + k];
            acc0[m] += a.x * w0[0]; acc0[m] += a.y * w0[1];
            acc0[m] += a.z * w0[2]; acc0[m] += a.w * w0[3];
            acc1[m] += a.x * w1[0]; acc1[m] += a.y * w1[1];
            acc1[m] += a.z * w1[2]; acc1[m] += a.w * w1[3];
        }
    }
    float b0 = b_in[n0], b1 = b_in[n1];
#pragma unroll
    for (int m = 0; m < 16; m++) {
        h[(bt0 + m) * H_ + n0] = silu_f(acc0[m] + b0);
        h[(bt0 + m) * H_ + n1] = silu_f(acc1[m] + b1);
    }
}

// ---------------- K4: gates/drive, 8 tokens/block
__global__ __launch_bounds__(256) void k_gates(
    const float* __restrict__ h, const float* __restrict__ Wg, const float* __restrict__ bg,
    const float* __restrict__ Wi, const float* __restrict__ bi,
    float* __restrict__ gates, float* __restrict__ drive) {
    __shared__ float sh[8 * H_];
    int bt0 = blockIdx.x * 8;
    {
        const float4* src = (const float4*)(h + bt0 * H_);
        float4* dst = (float4*)sh;
        for (int i = threadIdx.x; i < 8 * H_ / 4; i += 256) dst[i] = src[i];
    }
    __syncthreads();
    int m = threadIdx.x >> 5, n = threadIdx.x & 31;
    float ag = 0.f, ai = 0.f;
    for (int k = 0; k < H_; k++) {
        float a = sh[m * H_ + k];
        ag += a * Wg[k * SS_ + n];
        ai += a * Wi[k * SS_ + n];
    }
    float g = sigm_f(ag + bg[n]);
    float d = (1.0f - g) * (ai + bi[n]);
    gates[(bt0 + m) * SS_ + n] = g;
    drive[(bt0 + m) * SS_ + n] = d;
}

// ---------------- K5: per-chunk (A,B)
__global__ __launch_bounds__(256) void k_chunk_ab(
    const float* __restrict__ gates, const float* __restrict__ drive,
    float* __restrict__ chA, float* __restrict__ chB) {
    int gid = blockIdx.x * 256 + threadIdx.x;    // B*NCH*SS = 65536
    int s = gid & 31;
    int n = (gid >> 5) & (NCH_ - 1);
    int b = gid >> 13;
    int base = (b * T_ + n * CHUNK_) * SS_ + s;
    float suml = 0.f, cum_wb = 0.f, cum_a = 1.f;
    for (int i = 0; i < CHUNK_; i++) {
        float g = gates[base + i * SS_];
        float d = drive[base + i * SS_];
        suml += logf(fmaxf(g, 1e-6f));
        cum_a = expf(suml);
        cum_wb += d / fmaxf(cum_a, 1e-8f);
    }
    chA[gid] = cum_a;
    chB[gid] = cum_a * cum_wb;
}

// ---------------- K6: serial scan over 256 chunks; chH = carry INTO chunk n
__global__ void k_chunk_scan(const float* __restrict__ chA, const float* __restrict__ chB,
                             float* __restrict__ chH) {
    int tid = threadIdx.x;     // 256 = B*SS
    int b = tid >> 5, s = tid & 31;
    float hc = 0.f;
    for (int n = 0; n < NCH_; n++) {
        int idx = (b * NCH_ + n) * SS_ + s;
        chH[idx] = hc;
        hc = chA[idx] * hc + chB[idx];
    }
}

// ---------------- K7: materialize states
__global__ __launch_bounds__(256) void k_states(
    const float* __restrict__ gates, const float* __restrict__ drive,
    const float* __restrict__ chH, float* __restrict__ states) {
    int gid = blockIdx.x * 256 + threadIdx.x;
    int s = gid & 31;
    int n = (gid >> 5) & (NCH_ - 1);
    int b = gid >> 13;
    int base = (b * T_ + n * CHUNK_) * SS_ + s;
    float hc = chH[gid];
    float suml = 0.f, cum_wb = 0.f;
    for (int i = 0; i < CHUNK_; i++) {
        float g = gates[base + i * SS_];
        float d = drive[base + i * SS_];
        suml += logf(fmaxf(g, 1e-6f));
        float cum_a = expf(suml);
        cum_wb += d / fmaxf(cum_a, 1e-8f);
        states[base + i * SS_] = cum_a * (hc + cum_wb);
    }
}

// ---------------- K8: h = LN(h + states@Wo + bo), in-place, 4 tokens/block
__global__ __launch_bounds__(256) void k_wo_ln(
    const float* __restrict__ states, const float* __restrict__ Wo, const float* __restrict__ bo,
    const float* __restrict__ ln_g, const float* __restrict__ ln_b, float* __restrict__ h) {
    __shared__ float sst[4][SS_];
    __shared__ float red[4];
    int bt0 = blockIdx.x * 4;
    if (threadIdx.x < 128) sst[threadIdx.x >> 5][threadIdx.x & 31] = states[bt0 * SS_ + threadIdx.x];
    __syncthreads();
    int j0 = threadIdx.x, j1 = threadIdx.x + 256;
    float v0[4], v1[4];
    float bo0 = bo[j0], bo1 = bo[j1];
#pragma unroll
    for (int m = 0; m < 4; m++) {
        v0[m] = h[(bt0 + m) * H_ + j0] + bo0;
        v1[m] = h[(bt0 + m) * H_ + j1] + bo1;
    }
    for (int s = 0; s < SS_; s++) {
        float wo0 = Wo[s * H_ + j0], wo1 = Wo[s * H_ + j1];
#pragma unroll
        for (int m = 0; m < 4; m++) {
            v0[m] += sst[m][s] * wo0;
            v1[m] += sst[m][s] * wo1;
        }
    }
    float g0 = ln_g[j0], g1 = ln_g[j1], lb0 = ln_b[j0], lb1 = ln_b[j1];
#pragma unroll
    for (int m = 0; m < 4; m++) {
        float mu = blockReduce256(v0[m] + v1[m], red) * (1.0f / 512.0f);
        float d0 = v0[m] - mu, d1 = v1[m] - mu;
        float var = blockReduce256(d0 * d0 + d1 * d1, red) * (1.0f / 512.0f);
        float rstd = rsqrtf(var + 1e-5f);
        h[(bt0 + m) * H_ + j0] = d0 * rstd * g0 + lb0;
        h[(bt0 + m) * H_ + j1] = d1 * rstd * g1 + lb1;
    }
}

// ---------------- K9: residual MLP block (in-place), 16 tokens/block
__global__ __launch_bounds__(256) void k_mlp(
    const float* __restrict__ W, const float* __restrict__ bias, float* __restrict__ h) {
    __shared__ float sh[16 * H_];
    int bt0 = blockIdx.x * 16;
    {
        const float4* src = (const float4*)(h + bt0 * H_);
        float4* dst = (float4*)sh;
        for (int i = threadIdx.x; i < 16 * H_ / 4; i += 256) dst[i] = src[i];
    }
    __syncthreads();
    int n0 = threadIdx.x, n1 = threadIdx.x + 256;
    float acc0[16] = {}, acc1[16] = {};
    for (int k = 0; k < H_; k += 4) {
        float w0[4], w1[4];
#pragma unroll
        for (int kk = 0; kk < 4; kk++) {
            w0[kk] = W[(k + kk) * H_ + n0];
            w1[kk] = W[(k + kk) * H_ + n1];
        }
#pragma unroll
        for (int m = 0; m < 16; m++) {
            float4 a = *(const float4*)&sh[m * H_ + k];
            acc0[m] += a.x * w0[0]; acc0[m] += a.y * w0[1];
            acc0[m] += a.z * w0[2]; acc0[m] += a.w * w0[3];
            acc1[m] += a.x * w1[0]; acc1[m] += a.y * w1[1];
            acc1[m] += a.z * w1[2]; acc1[m] += a.w * w1[3];
        }
    }
    float b0 = bias[n0], b1 = bias[n1];
#pragma unroll
    for (int m = 0; m < 16; m++) {
        h[(bt0 + m) * H_ + n0] = sh[m * H_ + n0] + silu_f(acc0[m] + b0);
        h[(bt0 + m) * H_ + n1] = sh[m * H_ + n1] + silu_f(acc1[m] + b1);
    }
}

// ---------------- K10: out = h @ Wout + bout, 16 tokens/block
__global__ __launch_bounds__(256) void k_out(
    const float* __restrict__ h, const float* __restrict__ Wout,
    const float* __restrict__ bout, float* __restrict__ out) {
    __shared__ float sh[16 * H_];
    int bt0 = blockIdx.x * 16;
    {
        const float4* src = (const float4*)(h + bt0 * H_);
        float4* dst = (float4*)sh;
        for (int i = threadIdx.x; i < 16 * H_ / 4; i += 256) dst[i] = src[i];
    }
    __syncthreads();
    int n = threadIdx.x;
    float acc[16] = {};
    for (int k = 0; k < H_; k += 4) {
        float w[4];
#pragma unroll
        for (int kk = 0; kk < 4; kk++) w[kk] = Wout[(k + kk) * V_ + n];
#pragma unroll
        for (int m = 0; m < 16; m++) {
            float4 a = *(const float4*)&sh[m * H_ + k];
            acc[m] += a.x * w[0]; acc[m] += a.y * w[1];
            acc[m] += a.z * w[2]; acc[m] += a.w * w[3];
        }
    }
    float bv = bout[n];
#pragma unroll
    for (int m = 0; m < 16; m++) out[(bt0 + m) * V_ + n] = acc[m] + bv;
}

extern "C" void kernel_launch(void* const* d_in, const int* in_sizes, int n_in,
                              void* d_out, int out_size, void* d_ws, size_t ws_size,
                              hipStream_t stream) {
    (void)in_sizes; (void)n_in; (void)out_size; (void)ws_size;
    const int*   chars       = (const int*)  d_in[0];
    const float* emb_byte    = (const float*)d_in[1];
    const float* hash_tables = (const float*)d_in[2];
    const float* Wq          = (const float*)d_in[3];
    const float* bq          = (const float*)d_in[4];
    const float* conv_w      = (const float*)d_in[5];
    const float* conv_b      = (const float*)d_in[6];
    const float* Win         = (const float*)d_in[7];
    const float* b_in        = (const float*)d_in[8];
    const float* Wg          = (const float*)d_in[9];
    const float* bg          = (const float*)d_in[10];
    const float* Wi          = (const float*)d_in[11];
    const float* bi          = (const float*)d_in[12];
    const float* Wo          = (const float*)d_in[13];
    const float* bo          = (const float*)d_in[14];
    const float* ln_g        = (const float*)d_in[15];
    const float* ln_b        = (const float*)d_in[16];
    const float* mlp_w       = (const float*)d_in[17];
    const float* mlp_b       = (const float*)d_in[18];
    const float* Wout        = (const float*)d_in[19];
    const float* bout        = (const float*)d_in[20];
    float* out = (float*)d_out;

    const size_t NTOK = (size_t)B_ * T_;           // 65536
    float* ws = (float*)d_ws;
    float* feat   = ws;                 ws += NTOK * FEAT_;   // 8,650,752
    float* hfpre  = ws;                 ws += NTOK * E_;      // 4,194,304
    float* h      = ws;                 ws += NTOK * H_;      // 33,554,432
    float* gates  = ws;                 ws += NTOK * SS_;
    float* drive  = ws;                 ws += NTOK * SS_;
    float* states = ws;                 ws += NTOK * SS_;
    float* chA    = ws;                 ws += B_ * NCH_ * SS_;
    float* chB    = ws;                 ws += B_ * NCH_ * SS_;
    float* chH    = ws;                 ws += B_ * NCH_ * SS_;

    k_token_feats<<<NTOK / 4, 256, 0, stream>>>(chars, emb_byte, hash_tables, Wq, bq, feat, hfpre);
    k_conv<<<NTOK * E_ / 256, 256, 0, stream>>>(hfpre, conv_w, conv_b, feat);
    k_win<<<NTOK / 16, 256, 0, stream>>>(feat, Win, b_in, h);
    k_gates<<<NTOK / 8, 256, 0, stream>>>(h, Wg, bg, Wi, bi, gates, drive);
    k_chunk_ab<<<B_ * NCH_ * SS_ / 256, 256, 0, stream>>>(gates, drive, chA, chB);
    k_chunk_scan<<<1, 256, 0, stream>>>(chA, chB, chH);
    k_states<<<B_ * NCH_ * SS_ / 256, 256, 0, stream>>>(gates, drive, chH, states);
    k_wo_ln<<<NTOK / 4, 256, 0, stream>>>(states, Wo, bo, ln_g, ln_b, h);
    for (int l = 0; l < 3; l++) {
        k_mlp<<<NTOK / 16, 256, 0, stream>>>(mlp_w + (size_t)l * H_ * H_, mlp_b + (size_t)l * H_, h);
    }
    k_out<<<NTOK / 16, 256, 0, stream>>>(h, Wout, bout, out);
}

// Round 2
// 737.544 us; speedup vs baseline: 3.8579x; 3.8579x over previous
//
#include <hip/hip_runtime.h>
#include <hip/hip_bf16.h>
#include <math.h>

#define B_ 8
#define T_ 8192
#define V_ 256
#define EB_ 64
#define E_ 64
#define H_ 512
#define SS_ 32
#define FEATP_ 160   // padded feature dim (real 132, zero-padded to 160 = 5*32)
#define NCH_ 256
#define CHUNK_ 32

typedef __attribute__((ext_vector_type(8))) short bf8;     // 8 bf16 = 4 VGPRs (MFMA A/B frag)
typedef __attribute__((ext_vector_type(16))) float accv;   // MFMA 32x32 C/D frag

#define AS1(p) (__attribute__((address_space(1))) void*)(void*)(p)
#define AS3(p) (__attribute__((address_space(3))) void*)(void*)(p)

__device__ __forceinline__ float silu_f(float x) { return x / (1.0f + expf(-x)); }
__device__ __forceinline__ float sigm_f(float x) { return 1.0f / (1.0f + expf(-x)); }
__device__ __forceinline__ float bf2f(__hip_bfloat16 v) { return __bfloat162float(v); }
__device__ __forceinline__ __hip_bfloat16 f2bf(float v) { return __float2bfloat16(v); }

// ===================== MFMA 128x128-tile GEMM core =====================
// C[m0:m0+128, n0:n0+128] = A[m0:,:] @ Wt[n0:,:]^T
// A: M x KD bf16 row-major (ld=KD). Wt: N x KD bf16 row-major (ld=KD) (i.e. W transposed).
// 256 threads = 4 waves in 2x2 grid of 64x64 subtiles; each wave 2x2 MFMA 32x32 tiles.
template <int KD>
__device__ __forceinline__ void mm128(const __hip_bfloat16* __restrict__ A,
                                      const __hip_bfloat16* __restrict__ Wt,
                                      int m0, int n0, accv (&acc)[2][2]) {
    __shared__ __align__(16) ushort lA[128 * 32];
    __shared__ __align__(16) ushort lB[128 * 32];
    int tid = threadIdx.x;
    int lane = tid & 63, w = tid >> 6;
    int wm = w & 1, wn = w >> 1;
    // staging: chunk c (16B = row c>>2, cols (c&3)*8..+8); wave w owns chunks [w*128, w*128+128)
    int c0 = w * 128 + lane;
    int c1 = c0 + 64;
    const ushort* Ab = (const ushort*)A;
    const ushort* Bb = (const ushort*)Wt;
    const ushort* gA0 = Ab + (size_t)(m0 + (c0 >> 2)) * KD + (c0 & 3) * 8;
    const ushort* gA1 = Ab + (size_t)(m0 + (c1 >> 2)) * KD + (c1 & 3) * 8;
    const ushort* gB0 = Bb + (size_t)(n0 + (c0 >> 2)) * KD + (c0 & 3) * 8;
    const ushort* gB1 = Bb + (size_t)(n0 + (c1 >> 2)) * KD + (c1 & 3) * 8;
    ushort* dA0 = &lA[(w * 128) * 8];        // HW adds lane*16B
    ushort* dA1 = &lA[(w * 128 + 64) * 8];
    ushort* dB0 = &lB[(w * 128) * 8];
    ushort* dB1 = &lB[(w * 128 + 64) * 8];
    // fragment read pointers: row-major ld=32; lane l holds [row=base+(l&31)][k=(l>>5)*8 ..+8]
    const ushort* pa = &lA[(64 * wm + (lane & 31)) * 32 + (lane >> 5) * 8];
    const ushort* pb = &lB[(64 * wn + (lane & 31)) * 32 + (lane >> 5) * 8];

    for (int kt = 0; kt < KD; kt += 32) {
        __builtin_amdgcn_global_load_lds(AS1(gA0 + kt), AS3(dA0), 16, 0, 0);
        __builtin_amdgcn_global_load_lds(AS1(gA1 + kt), AS3(dA1), 16, 0, 0);
        __builtin_amdgcn_global_load_lds(AS1(gB0 + kt), AS3(dB0), 16, 0, 0);
        __builtin_amdgcn_global_load_lds(AS1(gB1 + kt), AS3(dB1), 16, 0, 0);
        __syncthreads();
#pragma unroll
        for (int ks = 0; ks < 2; ks++) {
            bf8 a0 = *(const bf8*)(pa + ks * 16);
            bf8 a1 = *(const bf8*)(pa + 32 * 32 + ks * 16);
            bf8 b0 = *(const bf8*)(pb + ks * 16);
            bf8 b1 = *(const bf8*)(pb + 32 * 32 + ks * 16);
            acc[0][0] = __builtin_amdgcn_mfma_f32_32x32x16_bf16(a0, b0, acc[0][0], 0, 0, 0);
            acc[0][1] = __builtin_amdgcn_mfma_f32_32x32x16_bf16(a0, b1, acc[0][1], 0, 0, 0);
            acc[1][0] = __builtin_amdgcn_mfma_f32_32x32x16_bf16(a1, b0, acc[1][0], 0, 0, 0);
            acc[1][1] = __builtin_amdgcn_mfma_f32_32x32x16_bf16(a1, b1, acc[1][1], 0, 0, 0);
        }
        __syncthreads();
    }
}

__device__ __forceinline__ void zero_acc(accv (&acc)[2][2]) {
#pragma unroll
    for (int i = 0; i < 2; i++)
#pragma unroll
        for (int j = 0; j < 2; j++)
#pragma unroll
            for (int r = 0; r < 16; r++) acc[i][j][r] = 0.0f;
}

// C/D layout (32x32): col = lane&31, row = (r&3) + 8*(r>>2) + 4*(lane>>5)
#define CD_ROW(r, lane) (((r) & 3) + 8 * ((r) >> 2) + 4 * ((lane) >> 5))

// ---------------- MLP residual block: hout = hin + silu(hin @ W + b)
__global__ __launch_bounds__(256) void k_mlp_mfma(const __hip_bfloat16* __restrict__ hin,
                                                  const __hip_bfloat16* __restrict__ Wt,
                                                  const float* __restrict__ bias,
                                                  __hip_bfloat16* __restrict__ hout) {
    accv acc[2][2];
    zero_acc(acc);
    int lane = threadIdx.x & 63, w = threadIdx.x >> 6, wm = w & 1, wn = w >> 1;
    int m0 = blockIdx.x * 128, n0 = blockIdx.y * 128;
    mm128<H_>(hin, Wt, m0, n0, acc);
#pragma unroll
    for (int i = 0; i < 2; i++)
#pragma unroll
        for (int j = 0; j < 2; j++) {
            int col = n0 + 64 * wn + 32 * j + (lane & 31);
            float bv = bias[col];
#pragma unroll
            for (int r = 0; r < 16; r++) {
                int row = m0 + 64 * wm + 32 * i + CD_ROW(r, lane);
                float v = acc[i][j][r] + bv;
                float res = bf2f(hin[(size_t)row * H_ + col]);
                hout[(size_t)row * H_ + col] = f2bf(res + silu_f(v));
            }
        }
}

// ---------------- Win: hb = bf16(silu(featb @ Win + b_in)), KD=160
__global__ __launch_bounds__(256) void k_win_mfma(const __hip_bfloat16* __restrict__ featb,
                                                  const __hip_bfloat16* __restrict__ Wt,
                                                  const float* __restrict__ bias,
                                                  __hip_bfloat16* __restrict__ hb) {
    accv acc[2][2];
    zero_acc(acc);
    int lane = threadIdx.x & 63, w = threadIdx.x >> 6, wm = w & 1, wn = w >> 1;
    int m0 = blockIdx.x * 128, n0 = blockIdx.y * 128;
    mm128<FEATP_>(featb, Wt, m0, n0, acc);
#pragma unroll
    for (int i = 0; i < 2; i++)
#pragma unroll
        for (int j = 0; j < 2; j++) {
            int col = n0 + 64 * wn + 32 * j + (lane & 31);
            float bv = bias[col];
#pragma unroll
            for (int r = 0; r < 16; r++) {
                int row = m0 + 64 * wm + 32 * i + CD_ROW(r, lane);
                hb[(size_t)row * H_ + col] = f2bf(silu_f(acc[i][j][r] + bv));
            }
        }
}

// ---------------- Out: out = hb @ Wout + bout (fp32 out, N=256)
__global__ __launch_bounds__(256) void k_out_mfma(const __hip_bfloat16* __restrict__ hb,
                                                  const __hip_bfloat16* __restrict__ Wt,
                                                  const float* __restrict__ bout,
                                                  float* __restrict__ out) {
    accv acc[2][2];
    zero_acc(acc);
    int lane = threadIdx.x & 63, w = threadIdx.x >> 6, wm = w & 1, wn = w >> 1;
    int m0 = blockIdx.x * 128, n0 = blockIdx.y * 128;
    mm128<H_>(hb, Wt, m0, n0, acc);
#pragma unroll
    for (int i = 0; i < 2; i++)
#pragma unroll
        for (int j = 0; j < 2; j++) {
            int col = n0 + 64 * wn + 32 * j + (lane & 31);
            float bv = bout[col];
#pragma unroll
            for (int r = 0; r < 16; r++) {
                int row = m0 + 64 * wm + 32 * i + CD_ROW(r, lane);
                out[(size_t)row * V_ + col] = acc[i][j][r] + bv;
            }
        }
}

// ---------------- gates/drive: [g|i] = hb @ [Wg|Wi]; tile 256x64, K=512
__global__ __launch_bounds__(256) void k_gates_mfma(const __hip_bfloat16* __restrict__ hb,
                                                    const __hip_bfloat16* __restrict__ Wt_gd,
                                                    const float* __restrict__ bg,
                                                    const float* __restrict__ bi,
                                                    float* __restrict__ gates,
                                                    float* __restrict__ drive) {
    __shared__ __align__(16) ushort lA[256 * 32];  // 16 KB
    __shared__ __align__(16) ushort lB[64 * 32];   // 4 KB
    int tid = threadIdx.x, lane = tid & 63, w = tid >> 6;
    int m0 = blockIdx.x * 256;
    accv acc[2][2];
    zero_acc(acc);
    const ushort* Ab = (const ushort*)hb;
    const ushort* Bb = (const ushort*)Wt_gd;
    const ushort* pa = &lA[(64 * w + (lane & 31)) * 32 + (lane >> 5) * 8];
    const ushort* pb = &lB[((lane & 31)) * 32 + (lane >> 5) * 8];
    int cb = w * 64 + lane;
    const ushort* gB = Bb + (size_t)(cb >> 2) * H_ + (cb & 3) * 8;
    for (int kt = 0; kt < H_; kt += 32) {
#pragma unroll
        for (int j = 0; j < 4; j++) {
            int c = w * 256 + j * 64 + lane;
            __builtin_amdgcn_global_load_lds(
                AS1(Ab + (size_t)(m0 + (c >> 2)) * H_ + (c & 3) * 8 + kt),
                AS3(&lA[(w * 256 + j * 64) * 8]), 16, 0, 0);
        }
        __builtin_amdgcn_global_load_lds(AS1(gB + kt), AS3(&lB[(w * 64) * 8]), 16, 0, 0);
        __syncthreads();
#pragma unroll
        for (int ks = 0; ks < 2; ks++) {
            bf8 a0 = *(const bf8*)(pa + ks * 16);
            bf8 a1 = *(const bf8*)(pa + 32 * 32 + ks * 16);
            bf8 b0 = *(const bf8*)(pb + ks * 16);
            bf8 b1 = *(const bf8*)(pb + 32 * 32 + ks * 16);
            acc[0][0] = __builtin_amdgcn_mfma_f32_32x32x16_bf16(a0, b0, acc[0][0], 0, 0, 0);
            acc[0][1] = __builtin_amdgcn_mfma_f32_32x32x16_bf16(a0, b1, acc[0][1], 0, 0, 0);
            acc[1][0] = __builtin_amdgcn_mfma_f32_32x32x16_bf16(a1, b0, acc[1][0], 0, 0, 0);
            acc[1][1] = __builtin_amdgcn_mfma_f32_32x32x16_bf16(a1, b1, acc[1][1], 0, 0, 0);
        }
        __syncthreads();
    }
    int c = lane & 31;
    float bgv = bg[c], biv = bi[c];
#pragma unroll
    for (int i = 0; i < 2; i++)
#pragma unroll
        for (int r = 0; r < 16; r++) {
            int row = m0 + 64 * w + 32 * i + CD_ROW(r, lane);
            float g = sigm_f(acc[i][0][r] + bgv);
            float d = (1.0f - g) * (acc[i][1][r] + biv);
            gates[(size_t)row * SS_ + c] = g;
            drive[(size_t)row * SS_ + c] = d;
        }
}

// ===================== weight prep: bf16 + transpose =====================
// Wt_mlp[3][512][512], Wt_out[256][512], Wt_win[512][160] (zero-pad k>=132), Wt_gd[64][512]
__global__ __launch_bounds__(256) void k_prep_w(const float* __restrict__ mlp_w,
                                                const float* __restrict__ Wout,
                                                const float* __restrict__ Win,
                                                const float* __restrict__ Wg,
                                                const float* __restrict__ Wi,
                                                __hip_bfloat16* __restrict__ Wt_mlp,
                                                __hip_bfloat16* __restrict__ Wt_out,
                                                __hip_bfloat16* __restrict__ Wt_win,
                                                __hip_bfloat16* __restrict__ Wt_gd) {
    int idx = blockIdx.x * 256 + threadIdx.x;
    if (idx < 786432) {  // mlp: l,n,k
        int l = idx >> 18, rem = idx & 262143;
        int n = rem >> 9, k = rem & 511;
        Wt_mlp[idx] = f2bf(mlp_w[l * 262144 + k * 512 + n]);
    } else if (idx < 786432 + 131072) {
        int rem = idx - 786432;
        int n = rem >> 9, k = rem & 511;
        Wt_out[rem] = f2bf(Wout[k * 256 + n]);
    } else if (idx < 786432 + 131072 + 81920) {
        int rem = idx - (786432 + 131072);
        int n = rem / 160, k = rem % 160;
        Wt_win[rem] = f2bf(k < 132 ? Win[k * 512 + n] : 0.0f);
    } else if (idx < 786432 + 131072 + 81920 + 32768) {
        int rem = idx - (786432 + 131072 + 81920);
        int n = rem >> 9, k = rem & 511;
        Wt_gd[rem] = f2bf(n < 32 ? Wg[k * 32 + n] : Wi[k * 32 + (n - 32)]);
    }
}

// ===================== token features (bf16 feat, stride 160) =====================
__global__ __launch_bounds__(256) void k_token_feats(
    const int* __restrict__ chars, const float* __restrict__ emb_byte,
    const float* __restrict__ hash_tables, const float* __restrict__ Wq,
    const float* __restrict__ bq, __hip_bfloat16* __restrict__ featb,
    float* __restrict__ hfpre) {
    int wave = threadIdx.x >> 6, lane = threadIdx.x & 63;
    int token = blockIdx.x * 4 + wave;
    int t = token & (T_ - 1);
    int b = token >> 13;
    const int* crow = chars + b * T_;
    int cj = 0;
    if (lane < 16 && (t - lane) >= 0) cj = crow[t - lane];
    int cv[16];
#pragma unroll
    for (int j = 0; j < 16; j++) cv[j] = __shfl(cj, j, 64);
    int acc = 0;
    int hidx[4];
#pragma unroll
    for (int j = 0; j < 16; j++) {
        acc += cv[j] * (1 + 256 * j);
        if (j == 1) hidx[0] = acc & 4095;
        if (j == 3) hidx[1] = acc & 4095;
        if (j == 7) hidx[2] = acc & 4095;
        if (j == 15) hidx[3] = acc & 4095;
    }
    float be = emb_byte[cv[0] * EB_ + lane];
    float se[4];
#pragma unroll
    for (int s = 0; s < 4; s++) se[s] = hash_tables[(s * 4096 + hidx[s]) * E_ + lane];
    float q = bq[lane];
#pragma unroll
    for (int k = 0; k < 64; k++) q += __shfl(be, k, 64) * Wq[k * 64 + lane];
    float sc[4];
#pragma unroll
    for (int s = 0; s < 4; s++) {
        float v = q * se[s];
#pragma unroll
        for (int off = 32; off; off >>= 1) v += __shfl_xor(v, off, 64);
        sc[s] = v * 0.125f;
    }
    float mx = fmaxf(fmaxf(sc[0], sc[1]), fmaxf(sc[2], sc[3]));
    float w0 = expf(sc[0] - mx), w1 = expf(sc[1] - mx), w2 = expf(sc[2] - mx), w3 = expf(sc[3] - mx);
    float inv = 1.0f / (w0 + w1 + w2 + w3);
    float hf = (w0 * se[0] + w1 * se[1] + w2 * se[2] + w3 * se[3]) * inv;
    featb[(size_t)token * FEATP_ + lane] = f2bf(be);
    hfpre[(size_t)token * E_ + lane] = hf;
    if (lane < 32) {
        float m = 0.0f;
        if (lane < 4) {
            int k = 1 << lane;
            m = (t >= k && cv[0] == cv[k]) ? 1.0f : 0.0f;
        }
        featb[(size_t)token * FEATP_ + 128 + lane] = f2bf(m);
    }
}

// ===================== conv -> featb[64:128] =====================
__global__ __launch_bounds__(256) void k_conv(
    const float* __restrict__ hfpre, const float* __restrict__ conv_w,
    const float* __restrict__ conv_b, __hip_bfloat16* __restrict__ featb) {
    int idx = blockIdx.x * 256 + threadIdx.x;
    int e = idx & 63;
    int bt = idx >> 6;
    int t = bt & (T_ - 1);
    float acc = conv_b[e];
#pragma unroll
    for (int k = 0; k < 4; k++) {
        int tt = t - 3 + k;
        if (tt >= 0) acc += hfpre[(size_t)(bt - 3 + k) * E_ + e] * conv_w[e * 4 + k];
    }
    featb[(size_t)bt * FEATP_ + 64 + e] = f2bf(silu_f(acc));
}

// ===================== scan chain (fp32, unchanged) =====================
__global__ __launch_bounds__(256) void k_chunk_ab(
    const float* __restrict__ gates, const float* __restrict__ drive,
    float* __restrict__ chA, float* __restrict__ chB) {
    int gid = blockIdx.x * 256 + threadIdx.x;
    int s = gid & 31;
    int n = (gid >> 5) & (NCH_ - 1);
    int b = gid >> 13;
    int base = (b * T_ + n * CHUNK_) * SS_ + s;
    float suml = 0.f, cum_wb = 0.f, cum_a = 1.f;
    for (int i = 0; i < CHUNK_; i++) {
        float g = gates[base + i * SS_];
        float d = drive[base + i * SS_];
        suml += logf(fmaxf(g, 1e-6f));
        cum_a = expf(suml);
        cum_wb += d / fmaxf(cum_a, 1e-8f);
    }
    chA[gid] = cum_a;
    chB[gid] = cum_a * cum_wb;
}

__global__ void k_chunk_scan(const float* __restrict__ chA, const float* __restrict__ chB,
                             float* __restrict__ chH) {
    int tid = threadIdx.x;
    int b = tid >> 5, s = tid & 31;
    float hc = 0.f;
    for (int n = 0; n < NCH_; n++) {
        int idx = (b * NCH_ + n) * SS_ + s;
        chH[idx] = hc;
        hc = chA[idx] * hc + chB[idx];
    }
}

__global__ __launch_bounds__(256) void k_states(
    const float* __restrict__ gates, const float* __restrict__ drive,
    const float* __restrict__ chH, float* __restrict__ states) {
    int gid = blockIdx.x * 256 + threadIdx.x;
    int s = gid & 31;
    int n = (gid >> 5) & (NCH_ - 1);
    int b = gid >> 13;
    int base = (b * T_ + n * CHUNK_) * SS_ + s;
    float hc = chH[gid];
    float suml = 0.f, cum_wb = 0.f;
    for (int i = 0; i < CHUNK_; i++) {
        float g = gates[base + i * SS_];
        float d = drive[base + i * SS_];
        suml += logf(fmaxf(g, 1e-6f));
        float cum_a = expf(suml);
        cum_wb += d / fmaxf(cum_a, 1e-8f);
        states[base + i * SS_] = cum_a * (hc + cum_wb);
    }
}

// ===================== LN(h + states@Wo + bo) on bf16 h, in-place =====================
__device__ __forceinline__ float blockReduce256(float v, volatile float* red) {
#pragma unroll
    for (int off = 32; off; off >>= 1) v += __shfl_xor(v, off, 64);
    int wid = threadIdx.x >> 6;
    if ((threadIdx.x & 63) == 0) red[wid] = v;
    __syncthreads();
    float t = red[0] + red[1] + red[2] + red[3];
    __syncthreads();
    return t;
}

__global__ __launch_bounds__(256) void k_wo_ln(
    const float* __restrict__ states, const float* __restrict__ Wo, const float* __restrict__ bo,
    const float* __restrict__ ln_g, const float* __restrict__ ln_b,
    __hip_bfloat16* __restrict__ hb) {
    __shared__ float sst[4][SS_];
    __shared__ float red[4];
    int bt0 = blockIdx.x * 4;
    if (threadIdx.x < 128) sst[threadIdx.x >> 5][threadIdx.x & 31] = states[bt0 * SS_ + threadIdx.x];
    __syncthreads();
    int j0 = threadIdx.x, j1 = threadIdx.x + 256;
    float v0[4], v1[4];
    float bo0 = bo[j0], bo1 = bo[j1];
#pragma unroll
    for (int m = 0; m < 4; m++) {
        v0[m] = bf2f(hb[(size_t)(bt0 + m) * H_ + j0]) + bo0;
        v1[m] = bf2f(hb[(size_t)(bt0 + m) * H_ + j1]) + bo1;
    }
    for (int s = 0; s < SS_; s++) {
        float wo0 = Wo[s * H_ + j0], wo1 = Wo[s * H_ + j1];
#pragma unroll
        for (int m = 0; m < 4; m++) {
            v0[m] += sst[m][s] * wo0;
            v1[m] += sst[m][s] * wo1;
        }
    }
    float g0 = ln_g[j0], g1 = ln_g[j1], lb0 = ln_b[j0], lb1 = ln_b[j1];
#pragma unroll
    for (int m = 0; m < 4; m++) {
        float mu = blockReduce256(v0[m] + v1[m], red) * (1.0f / 512.0f);
        float d0 = v0[m] - mu, d1 = v1[m] - mu;
        float var = blockReduce256(d0 * d0 + d1 * d1, red) * (1.0f / 512.0f);
        float rstd = rsqrtf(var + 1e-5f);
        hb[(size_t)(bt0 + m) * H_ + j0] = f2bf(d0 * rstd * g0 + lb0);
        hb[(size_t)(bt0 + m) * H_ + j1] = f2bf(d1 * rstd * g1 + lb1);
    }
}

// ===================== launch =====================
extern "C" void kernel_launch(void* const* d_in, const int* in_sizes, int n_in,
                              void* d_out, int out_size, void* d_ws, size_t ws_size,
                              hipStream_t stream) {
    (void)in_sizes; (void)n_in; (void)out_size; (void)ws_size;
    const int*   chars       = (const int*)  d_in[0];
    const float* emb_byte    = (const float*)d_in[1];
    const float* hash_tables = (const float*)d_in[2];
    const float* Wq          = (const float*)d_in[3];
    const float* bq          = (const float*)d_in[4];
    const float* conv_w      = (const float*)d_in[5];
    const float* conv_b      = (const float*)d_in[6];
    const float* Win         = (const float*)d_in[7];
    const float* b_in        = (const float*)d_in[8];
    const float* Wg          = (const float*)d_in[9];
    const float* bg          = (const float*)d_in[10];
    const float* Wi          = (const float*)d_in[11];
    const float* bi          = (const float*)d_in[12];
    const float* Wo          = (const float*)d_in[13];
    const float* bo          = (const float*)d_in[14];
    const float* ln_g        = (const float*)d_in[15];
    const float* ln_b        = (const float*)d_in[16];
    const float* mlp_w       = (const float*)d_in[17];
    const float* mlp_b       = (const float*)d_in[18];
    const float* Wout        = (const float*)d_in[19];
    const float* bout        = (const float*)d_in[20];
    float* out = (float*)d_out;

    const size_t NTOK = (size_t)B_ * T_;  // 65536
    char* p = (char*)d_ws;
    auto alloc = [&](size_t bytes) { void* r = (void*)p; p += (bytes + 255) & ~(size_t)255; return r; };
    __hip_bfloat16* featb = (__hip_bfloat16*)alloc(NTOK * FEATP_ * 2);   // 21.0 MB
    float*          hfpre = (float*)alloc(NTOK * E_ * 4);                // 16.8 MB
    __hip_bfloat16* hbA   = (__hip_bfloat16*)alloc(NTOK * H_ * 2);       // 67.1 MB
    __hip_bfloat16* hbB   = (__hip_bfloat16*)alloc(NTOK * H_ * 2);       // 67.1 MB
    float*          gates = (float*)alloc(NTOK * SS_ * 4);
    float*          drive = (float*)alloc(NTOK * SS_ * 4);
    float*          states= (float*)alloc(NTOK * SS_ * 4);
    float*          chA   = (float*)alloc((size_t)B_ * NCH_ * SS_ * 4);
    float*          chB   = (float*)alloc((size_t)B_ * NCH_ * SS_ * 4);
    float*          chH   = (float*)alloc((size_t)B_ * NCH_ * SS_ * 4);
    __hip_bfloat16* Wt_mlp= (__hip_bfloat16*)alloc(3 * 512 * 512 * 2);
    __hip_bfloat16* Wt_out= (__hip_bfloat16*)alloc(256 * 512 * 2);
    __hip_bfloat16* Wt_win= (__hip_bfloat16*)alloc(512 * FEATP_ * 2);
    __hip_bfloat16* Wt_gd = (__hip_bfloat16*)alloc(64 * 512 * 2);

    k_prep_w<<<4032, 256, 0, stream>>>(mlp_w, Wout, Win, Wg, Wi, Wt_mlp, Wt_out, Wt_win, Wt_gd);
    k_token_feats<<<NTOK / 4, 256, 0, stream>>>(chars, emb_byte, hash_tables, Wq, bq, featb, hfpre);
    k_conv<<<NTOK * E_ / 256, 256, 0, stream>>>(hfpre, conv_w, conv_b, featb);
    k_win_mfma<<<dim3(NTOK / 128, 4), 256, 0, stream>>>(featb, Wt_win, b_in, hbA);
    k_gates_mfma<<<NTOK / 256, 256, 0, stream>>>(hbA, Wt_gd, bg, bi, gates, drive);
    k_chunk_ab<<<B_ * NCH_ * SS_ / 256, 256, 0, stream>>>(gates, drive, chA, chB);
    k_chunk_scan<<<1, 256, 0, stream>>>(chA, chB, chH);
    k_states<<<B_ * NCH_ * SS_ / 256, 256, 0, stream>>>(gates, drive, chH, states);
    k_wo_ln<<<NTOK / 4, 256, 0, stream>>>(states, Wo, bo, ln_g, ln_b, hbA);
    k_mlp_mfma<<<dim3(NTOK / 128, 4), 256, 0, stream>>>(hbA, Wt_mlp, mlp_b, hbB);
    k_mlp_mfma<<<dim3(NTOK / 128, 4), 256, 0, stream>>>(hbB, Wt_mlp + 262144, mlp_b + 512, hbA);
    k_mlp_mfma<<<dim3(NTOK / 128, 4), 256, 0, stream>>>(hbA, Wt_mlp + 524288, mlp_b + 1024, hbB);
    k_out_mfma<<<dim3(NTOK / 128, 2), 256, 0, stream>>>(hbB, Wt_out, bout, out);
}

// Round 3
// 685.868 us; speedup vs baseline: 4.1486x; 1.0753x over previous
//
#include <hip/hip_runtime.h>
#include <hip/hip_bf16.h>
#include <math.h>

#define B_ 8
#define T_ 8192
#define V_ 256
#define EB_ 64
#define E_ 64
#define H_ 512
#define SS_ 32
#define FEATP_ 160   // padded feature dim (real 132, zero-padded to 160 = 5*32)
#define NCH_ 256
#define CHUNK_ 32

typedef __attribute__((ext_vector_type(8))) short bf8;     // 8 bf16 = 4 VGPRs (MFMA A/B frag)
typedef __attribute__((ext_vector_type(16))) float accv;   // MFMA 32x32 C/D frag

#define AS1(p) (__attribute__((address_space(1))) void*)(void*)(p)
#define AS3(p) (__attribute__((address_space(3))) void*)(void*)(p)

__device__ __forceinline__ float silu_f(float x) { return x / (1.0f + expf(-x)); }
__device__ __forceinline__ float sigm_f(float x) { return 1.0f / (1.0f + expf(-x)); }
__device__ __forceinline__ float bf2f(__hip_bfloat16 v) { return __bfloat162float(v); }
__device__ __forceinline__ __hip_bfloat16 f2bf(float v) { return __float2bfloat16(v); }

// ===================== MFMA 128x128-tile GEMM core =====================
template <int KD>
__device__ __forceinline__ void mm128(const __hip_bfloat16* __restrict__ A,
                                      const __hip_bfloat16* __restrict__ Wt,
                                      int m0, int n0, accv (&acc)[2][2]) {
    __shared__ __align__(16) ushort lA[128 * 32];
    __shared__ __align__(16) ushort lB[128 * 32];
    int tid = threadIdx.x;
    int lane = tid & 63, w = tid >> 6;
    int wm = w & 1, wn = w >> 1;
    int c0 = w * 128 + lane;
    int c1 = c0 + 64;
    const ushort* Ab = (const ushort*)A;
    const ushort* Bb = (const ushort*)Wt;
    const ushort* gA0 = Ab + (size_t)(m0 + (c0 >> 2)) * KD + (c0 & 3) * 8;
    const ushort* gA1 = Ab + (size_t)(m0 + (c1 >> 2)) * KD + (c1 & 3) * 8;
    const ushort* gB0 = Bb + (size_t)(n0 + (c0 >> 2)) * KD + (c0 & 3) * 8;
    const ushort* gB1 = Bb + (size_t)(n0 + (c1 >> 2)) * KD + (c1 & 3) * 8;
    ushort* dA0 = &lA[(w * 128) * 8];
    ushort* dA1 = &lA[(w * 128 + 64) * 8];
    ushort* dB0 = &lB[(w * 128) * 8];
    ushort* dB1 = &lB[(w * 128 + 64) * 8];
    const ushort* pa = &lA[(64 * wm + (lane & 31)) * 32 + (lane >> 5) * 8];
    const ushort* pb = &lB[(64 * wn + (lane & 31)) * 32 + (lane >> 5) * 8];

    for (int kt = 0; kt < KD; kt += 32) {
        __builtin_amdgcn_global_load_lds(AS1(gA0 + kt), AS3(dA0), 16, 0, 0);
        __builtin_amdgcn_global_load_lds(AS1(gA1 + kt), AS3(dA1), 16, 0, 0);
        __builtin_amdgcn_global_load_lds(AS1(gB0 + kt), AS3(dB0), 16, 0, 0);
        __builtin_amdgcn_global_load_lds(AS1(gB1 + kt), AS3(dB1), 16, 0, 0);
        __syncthreads();
#pragma unroll
        for (int ks = 0; ks < 2; ks++) {
            bf8 a0 = *(const bf8*)(pa + ks * 16);
            bf8 a1 = *(const bf8*)(pa + 32 * 32 + ks * 16);
            bf8 b0 = *(const bf8*)(pb + ks * 16);
            bf8 b1 = *(const bf8*)(pb + 32 * 32 + ks * 16);
            acc[0][0] = __builtin_amdgcn_mfma_f32_32x32x16_bf16(a0, b0, acc[0][0], 0, 0, 0);
            acc[0][1] = __builtin_amdgcn_mfma_f32_32x32x16_bf16(a0, b1, acc[0][1], 0, 0, 0);
            acc[1][0] = __builtin_amdgcn_mfma_f32_32x32x16_bf16(a1, b0, acc[1][0], 0, 0, 0);
            acc[1][1] = __builtin_amdgcn_mfma_f32_32x32x16_bf16(a1, b1, acc[1][1], 0, 0, 0);
        }
        __syncthreads();
    }
}

__device__ __forceinline__ void zero_acc(accv (&acc)[2][2]) {
#pragma unroll
    for (int i = 0; i < 2; i++)
#pragma unroll
        for (int j = 0; j < 2; j++)
#pragma unroll
            for (int r = 0; r < 16; r++) acc[i][j][r] = 0.0f;
}

#define CD_ROW(r, lane) (((r) & 3) + 8 * ((r) >> 2) + 4 * ((lane) >> 5))

// ---------------- MLP residual block: hout = hin + silu(hin @ W + b)
__global__ __launch_bounds__(256) void k_mlp_mfma(const __hip_bfloat16* __restrict__ hin,
                                                  const __hip_bfloat16* __restrict__ Wt,
                                                  const float* __restrict__ bias,
                                                  __hip_bfloat16* __restrict__ hout) {
    accv acc[2][2];
    zero_acc(acc);
    int lane = threadIdx.x & 63, w = threadIdx.x >> 6, wm = w & 1, wn = w >> 1;
    int m0 = blockIdx.x * 128, n0 = blockIdx.y * 128;
    mm128<H_>(hin, Wt, m0, n0, acc);
#pragma unroll
    for (int i = 0; i < 2; i++)
#pragma unroll
        for (int j = 0; j < 2; j++) {
            int col = n0 + 64 * wn + 32 * j + (lane & 31);
            float bv = bias[col];
#pragma unroll
            for (int r = 0; r < 16; r++) {
                int row = m0 + 64 * wm + 32 * i + CD_ROW(r, lane);
                float v = acc[i][j][r] + bv;
                float res = bf2f(hin[(size_t)row * H_ + col]);
                hout[(size_t)row * H_ + col] = f2bf(res + silu_f(v));
            }
        }
}

// ---------------- Win: hb = bf16(silu(featb @ Win + b_in)), KD=160
__global__ __launch_bounds__(256) void k_win_mfma(const __hip_bfloat16* __restrict__ featb,
                                                  const __hip_bfloat16* __restrict__ Wt,
                                                  const float* __restrict__ bias,
                                                  __hip_bfloat16* __restrict__ hb) {
    accv acc[2][2];
    zero_acc(acc);
    int lane = threadIdx.x & 63, w = threadIdx.x >> 6, wm = w & 1, wn = w >> 1;
    int m0 = blockIdx.x * 128, n0 = blockIdx.y * 128;
    mm128<FEATP_>(featb, Wt, m0, n0, acc);
#pragma unroll
    for (int i = 0; i < 2; i++)
#pragma unroll
        for (int j = 0; j < 2; j++) {
            int col = n0 + 64 * wn + 32 * j + (lane & 31);
            float bv = bias[col];
#pragma unroll
            for (int r = 0; r < 16; r++) {
                int row = m0 + 64 * wm + 32 * i + CD_ROW(r, lane);
                hb[(size_t)row * H_ + col] = f2bf(silu_f(acc[i][j][r] + bv));
            }
        }
}

// ---------------- Out: out = hb @ Wout + bout (fp32 out, N=256)
__global__ __launch_bounds__(256) void k_out_mfma(const __hip_bfloat16* __restrict__ hb,
                                                  const __hip_bfloat16* __restrict__ Wt,
                                                  const float* __restrict__ bout,
                                                  float* __restrict__ out) {
    accv acc[2][2];
    zero_acc(acc);
    int lane = threadIdx.x & 63, w = threadIdx.x >> 6, wm = w & 1, wn = w >> 1;
    int m0 = blockIdx.x * 128, n0 = blockIdx.y * 128;
    mm128<H_>(hb, Wt, m0, n0, acc);
#pragma unroll
    for (int i = 0; i < 2; i++)
#pragma unroll
        for (int j = 0; j < 2; j++) {
            int col = n0 + 64 * wn + 32 * j + (lane & 31);
            float bv = bout[col];
#pragma unroll
            for (int r = 0; r < 16; r++) {
                int row = m0 + 64 * wm + 32 * i + CD_ROW(r, lane);
                out[(size_t)row * V_ + col] = acc[i][j][r] + bv;
            }
        }
}

// ---------------- gates/drive: [g|i] = hb @ [Wg|Wi]; tile 256x64, K=512
__global__ __launch_bounds__(256) void k_gates_mfma(const __hip_bfloat16* __restrict__ hb,
                                                    const __hip_bfloat16* __restrict__ Wt_gd,
                                                    const float* __restrict__ bg,
                                                    const float* __restrict__ bi,
                                                    float* __restrict__ gates,
                                                    float* __restrict__ drive) {
    __shared__ __align__(16) ushort lA[256 * 32];
    __shared__ __align__(16) ushort lB[64 * 32];
    int tid = threadIdx.x, lane = tid & 63, w = tid >> 6;
    int m0 = blockIdx.x * 256;
    accv acc[2][2];
    zero_acc(acc);
    const ushort* Ab = (const ushort*)hb;
    const ushort* Bb = (const ushort*)Wt_gd;
    const ushort* pa = &lA[(64 * w + (lane & 31)) * 32 + (lane >> 5) * 8];
    const ushort* pb = &lB[((lane & 31)) * 32 + (lane >> 5) * 8];
    int cb = w * 64 + lane;
    const ushort* gB = Bb + (size_t)(cb >> 2) * H_ + (cb & 3) * 8;
    for (int kt = 0; kt < H_; kt += 32) {
#pragma unroll
        for (int j = 0; j < 4; j++) {
            int c = w * 256 + j * 64 + lane;
            __builtin_amdgcn_global_load_lds(
                AS1(Ab + (size_t)(m0 + (c >> 2)) * H_ + (c & 3) * 8 + kt),
                AS3(&lA[(w * 256 + j * 64) * 8]), 16, 0, 0);
        }
        __builtin_amdgcn_global_load_lds(AS1(gB + kt), AS3(&lB[(w * 64) * 8]), 16, 0, 0);
        __syncthreads();
#pragma unroll
        for (int ks = 0; ks < 2; ks++) {
            bf8 a0 = *(const bf8*)(pa + ks * 16);
            bf8 a1 = *(const bf8*)(pa + 32 * 32 + ks * 16);
            bf8 b0 = *(const bf8*)(pb + ks * 16);
            bf8 b1 = *(const bf8*)(pb + 32 * 32 + ks * 16);
            acc[0][0] = __builtin_amdgcn_mfma_f32_32x32x16_bf16(a0, b0, acc[0][0], 0, 0, 0);
            acc[0][1] = __builtin_amdgcn_mfma_f32_32x32x16_bf16(a0, b1, acc[0][1], 0, 0, 0);
            acc[1][0] = __builtin_amdgcn_mfma_f32_32x32x16_bf16(a1, b0, acc[1][0], 0, 0, 0);
            acc[1][1] = __builtin_amdgcn_mfma_f32_32x32x16_bf16(a1, b1, acc[1][1], 0, 0, 0);
        }
        __syncthreads();
    }
    int c = lane & 31;
    float bgv = bg[c], biv = bi[c];
#pragma unroll
    for (int i = 0; i < 2; i++)
#pragma unroll
        for (int r = 0; r < 16; r++) {
            int row = m0 + 64 * w + 32 * i + CD_ROW(r, lane);
            float g = sigm_f(acc[i][0][r] + bgv);
            float d = (1.0f - g) * (acc[i][1][r] + biv);
            gates[(size_t)row * SS_ + c] = g;
            drive[(size_t)row * SS_ + c] = d;
        }
}

// ===================== weight prep: bf16 + transpose =====================
__global__ __launch_bounds__(256) void k_prep_w(const float* __restrict__ mlp_w,
                                                const float* __restrict__ Wout,
                                                const float* __restrict__ Win,
                                                const float* __restrict__ Wg,
                                                const float* __restrict__ Wi,
                                                __hip_bfloat16* __restrict__ Wt_mlp,
                                                __hip_bfloat16* __restrict__ Wt_out,
                                                __hip_bfloat16* __restrict__ Wt_win,
                                                __hip_bfloat16* __restrict__ Wt_gd) {
    int idx = blockIdx.x * 256 + threadIdx.x;
    if (idx < 786432) {
        int l = idx >> 18, rem = idx & 262143;
        int n = rem >> 9, k = rem & 511;
        Wt_mlp[idx] = f2bf(mlp_w[l * 262144 + k * 512 + n]);
    } else if (idx < 786432 + 131072) {
        int rem = idx - 786432;
        int n = rem >> 9, k = rem & 511;
        Wt_out[rem] = f2bf(Wout[k * 256 + n]);
    } else if (idx < 786432 + 131072 + 81920) {
        int rem = idx - (786432 + 131072);
        int n = rem / 160, k = rem % 160;
        Wt_win[rem] = f2bf(k < 132 ? Win[k * 512 + n] : 0.0f);
    } else if (idx < 786432 + 131072 + 81920 + 32768) {
        int rem = idx - (786432 + 131072 + 81920);
        int n = rem >> 9, k = rem & 511;
        Wt_gd[rem] = f2bf(n < 32 ? Wg[k * 32 + n] : Wi[k * 32 + (n - 32)]);
    }
}

// ===================== token features =====================
__global__ __launch_bounds__(256) void k_token_feats(
    const int* __restrict__ chars, const float* __restrict__ emb_byte,
    const float* __restrict__ hash_tables, const float* __restrict__ Wq,
    const float* __restrict__ bq, __hip_bfloat16* __restrict__ featb,
    float* __restrict__ hfpre) {
    int wave = threadIdx.x >> 6, lane = threadIdx.x & 63;
    int token = blockIdx.x * 4 + wave;
    int t = token & (T_ - 1);
    int b = token >> 13;
    const int* crow = chars + b * T_;
    int cj = 0;
    if (lane < 16 && (t - lane) >= 0) cj = crow[t - lane];
    int cv[16];
#pragma unroll
    for (int j = 0; j < 16; j++) cv[j] = __shfl(cj, j, 64);
    int acc = 0;
    int hidx[4];
#pragma unroll
    for (int j = 0; j < 16; j++) {
        acc += cv[j] * (1 + 256 * j);
        if (j == 1) hidx[0] = acc & 4095;
        if (j == 3) hidx[1] = acc & 4095;
        if (j == 7) hidx[2] = acc & 4095;
        if (j == 15) hidx[3] = acc & 4095;
    }
    float be = emb_byte[cv[0] * EB_ + lane];
    float se[4];
#pragma unroll
    for (int s = 0; s < 4; s++) se[s] = hash_tables[(s * 4096 + hidx[s]) * E_ + lane];
    float q = bq[lane];
#pragma unroll
    for (int k = 0; k < 64; k++) q += __shfl(be, k, 64) * Wq[k * 64 + lane];
    float sc[4];
#pragma unroll
    for (int s = 0; s < 4; s++) {
        float v = q * se[s];
#pragma unroll
        for (int off = 32; off; off >>= 1) v += __shfl_xor(v, off, 64);
        sc[s] = v * 0.125f;
    }
    float mx = fmaxf(fmaxf(sc[0], sc[1]), fmaxf(sc[2], sc[3]));
    float w0 = expf(sc[0] - mx), w1 = expf(sc[1] - mx), w2 = expf(sc[2] - mx), w3 = expf(sc[3] - mx);
    float inv = 1.0f / (w0 + w1 + w2 + w3);
    float hf = (w0 * se[0] + w1 * se[1] + w2 * se[2] + w3 * se[3]) * inv;
    featb[(size_t)token * FEATP_ + lane] = f2bf(be);
    hfpre[(size_t)token * E_ + lane] = hf;
    if (lane < 32) {
        float m = 0.0f;
        if (lane < 4) {
            int k = 1 << lane;
            m = (t >= k && cv[0] == cv[k]) ? 1.0f : 0.0f;
        }
        featb[(size_t)token * FEATP_ + 128 + lane] = f2bf(m);
    }
}

// ===================== conv -> featb[64:128] =====================
__global__ __launch_bounds__(256) void k_conv(
    const float* __restrict__ hfpre, const float* __restrict__ conv_w,
    const float* __restrict__ conv_b, __hip_bfloat16* __restrict__ featb) {
    int idx = blockIdx.x * 256 + threadIdx.x;
    int e = idx & 63;
    int bt = idx >> 6;
    int t = bt & (T_ - 1);
    float acc = conv_b[e];
#pragma unroll
    for (int k = 0; k < 4; k++) {
        int tt = t - 3 + k;
        if (tt >= 0) acc += hfpre[(size_t)(bt - 3 + k) * E_ + e] * conv_w[e * 4 + k];
    }
    featb[(size_t)bt * FEATP_ + 64 + e] = f2bf(silu_f(acc));
}

// ===================== scan chain =====================
__global__ __launch_bounds__(256) void k_chunk_ab(
    const float* __restrict__ gates, const float* __restrict__ drive,
    float* __restrict__ chA, float* __restrict__ chB) {
    int gid = blockIdx.x * 256 + threadIdx.x;
    int s = gid & 31;
    int n = (gid >> 5) & (NCH_ - 1);
    int b = gid >> 13;
    int base = (b * T_ + n * CHUNK_) * SS_ + s;
    float suml = 0.f, cum_wb = 0.f, cum_a = 1.f;
    for (int i = 0; i < CHUNK_; i++) {
        float g = gates[base + i * SS_];
        float d = drive[base + i * SS_];
        suml += logf(fmaxf(g, 1e-6f));
        cum_a = expf(suml);
        cum_wb += d / fmaxf(cum_a, 1e-8f);
    }
    chA[gid] = cum_a;
    chB[gid] = cum_a * cum_wb;
}

// serial scan over 256 chunks with batched (latency-hidden) loads
__global__ void k_chunk_scan(const float* __restrict__ chA, const float* __restrict__ chB,
                             float* __restrict__ chH) {
    int tid = threadIdx.x;     // 256 = B*SS
    int b = tid >> 5, s = tid & 31;
    const float* pA = chA + (size_t)b * NCH_ * SS_ + s;
    const float* pB = chB + (size_t)b * NCH_ * SS_ + s;
    float* pH = chH + (size_t)b * NCH_ * SS_ + s;
    float hc = 0.f;
    for (int n = 0; n < NCH_; n += 8) {
        float a[8], bb[8];
#pragma unroll
        for (int i = 0; i < 8; i++) {
            a[i] = pA[(n + i) * SS_];
            bb[i] = pB[(n + i) * SS_];
        }
#pragma unroll
        for (int i = 0; i < 8; i++) {
            pH[(n + i) * SS_] = hc;
            hc = a[i] * hc + bb[i];
        }
    }
}

__global__ __launch_bounds__(256) void k_states(
    const float* __restrict__ gates, const float* __restrict__ drive,
    const float* __restrict__ chH, float* __restrict__ states) {
    int gid = blockIdx.x * 256 + threadIdx.x;
    int s = gid & 31;
    int n = (gid >> 5) & (NCH_ - 1);
    int b = gid >> 13;
    int base = (b * T_ + n * CHUNK_) * SS_ + s;
    float hc = chH[gid];
    float suml = 0.f, cum_wb = 0.f;
    for (int i = 0; i < CHUNK_; i++) {
        float g = gates[base + i * SS_];
        float d = drive[base + i * SS_];
        suml += logf(fmaxf(g, 1e-6f));
        float cum_a = expf(suml);
        cum_wb += d / fmaxf(cum_a, 1e-8f);
        states[base + i * SS_] = cum_a * (hc + cum_wb);
    }
}

// ===================== LN(h + states@Wo + bo), 32 tokens/block =====================
__global__ __launch_bounds__(256) void k_wo_ln(
    const float* __restrict__ states, const float* __restrict__ Wo, const float* __restrict__ bo,
    const float* __restrict__ ln_g, const float* __restrict__ ln_b,
    __hip_bfloat16* __restrict__ hb) {
    __shared__ float sst[32][SS_];
    __shared__ float red[4][16];
    int tid = threadIdx.x;
    int bt0 = blockIdx.x * 32;
    {   // states for 32 tokens: 1024 floats, float4-coalesced
        const float4* src = (const float4*)(states + (size_t)bt0 * SS_);
        ((float4*)sst)[tid] = src[tid];
    }
    int j0 = tid, j1 = tid + 256;
    float wo0[SS_], wo1[SS_];
#pragma unroll
    for (int s = 0; s < SS_; s++) {
        wo0[s] = Wo[s * H_ + j0];
        wo1[s] = Wo[s * H_ + j1];
    }
    float bo0 = bo[j0], bo1 = bo[j1];
    float g0 = ln_g[j0], g1 = ln_g[j1], lb0 = ln_b[j0], lb1 = ln_b[j1];
    int w = tid >> 6, lane = tid & 63;
    __syncthreads();
    for (int mb = 0; mb < 32; mb += 8) {
        float v0[8], v1[8];
#pragma unroll
        for (int m = 0; m < 8; m++) {
            int row = bt0 + mb + m;
            float a0 = bf2f(hb[(size_t)row * H_ + j0]) + bo0;
            float a1 = bf2f(hb[(size_t)row * H_ + j1]) + bo1;
#pragma unroll
            for (int s = 0; s < SS_; s++) {
                float st = sst[mb + m][s];
                a0 += st * wo0[s];
                a1 += st * wo1[s];
            }
            v0[m] = a0;
            v1[m] = a1;
        }
#pragma unroll
        for (int m = 0; m < 8; m++) {
            float sm = v0[m] + v1[m];
            float sq = v0[m] * v0[m] + v1[m] * v1[m];
#pragma unroll
            for (int off = 32; off; off >>= 1) {
                sm += __shfl_xor(sm, off, 64);
                sq += __shfl_xor(sq, off, 64);
            }
            if (lane == 0) { red[w][m * 2] = sm; red[w][m * 2 + 1] = sq; }
        }
        __syncthreads();
#pragma unroll
        for (int m = 0; m < 8; m++) {
            float sm = red[0][m * 2] + red[1][m * 2] + red[2][m * 2] + red[3][m * 2];
            float sq = red[0][m * 2 + 1] + red[1][m * 2 + 1] + red[2][m * 2 + 1] + red[3][m * 2 + 1];
            float mu = sm * (1.0f / 512.0f);
            float var = sq * (1.0f / 512.0f) - mu * mu;
            float rstd = rsqrtf(fmaxf(var, 0.0f) + 1e-5f);
            int row = bt0 + mb + m;
            hb[(size_t)row * H_ + j0] = f2bf((v0[m] - mu) * rstd * g0 + lb0);
            hb[(size_t)row * H_ + j1] = f2bf((v1[m] - mu) * rstd * g1 + lb1);
        }
        __syncthreads();
    }
}

// ===================== launch =====================
extern "C" void kernel_launch(void* const* d_in, const int* in_sizes, int n_in,
                              void* d_out, int out_size, void* d_ws, size_t ws_size,
                              hipStream_t stream) {
    (void)in_sizes; (void)n_in; (void)out_size; (void)ws_size;
    const int*   chars       = (const int*)  d_in[0];
    const float* emb_byte    = (const float*)d_in[1];
    const float* hash_tables = (const float*)d_in[2];
    const float* Wq          = (const float*)d_in[3];
    const float* bq          = (const float*)d_in[4];
    const float* conv_w      = (const float*)d_in[5];
    const float* conv_b      = (const float*)d_in[6];
    const float* Win         = (const float*)d_in[7];
    const float* b_in        = (const float*)d_in[8];
    const float* Wg          = (const float*)d_in[9];
    const float* bg          = (const float*)d_in[10];
    const float* Wi          = (const float*)d_in[11];
    const float* bi          = (const float*)d_in[12];
    const float* Wo          = (const float*)d_in[13];
    const float* bo          = (const float*)d_in[14];
    const float* ln_g        = (const float*)d_in[15];
    const float* ln_b        = (const float*)d_in[16];
    const float* mlp_w       = (const float*)d_in[17];
    const float* mlp_b       = (const float*)d_in[18];
    const float* Wout        = (const float*)d_in[19];
    const float* bout        = (const float*)d_in[20];
    float* out = (float*)d_out;

    const size_t NTOK = (size_t)B_ * T_;  // 65536
    char* p = (char*)d_ws;
    auto alloc = [&](size_t bytes) { void* r = (void*)p; p += (bytes + 255) & ~(size_t)255; return r; };
    __hip_bfloat16* featb = (__hip_bfloat16*)alloc(NTOK * FEATP_ * 2);
    float*          hfpre = (float*)alloc(NTOK * E_ * 4);
    __hip_bfloat16* hbA   = (__hip_bfloat16*)alloc(NTOK * H_ * 2);
    __hip_bfloat16* hbB   = (__hip_bfloat16*)alloc(NTOK * H_ * 2);
    float*          gates = (float*)alloc(NTOK * SS_ * 4);
    float*          drive = (float*)alloc(NTOK * SS_ * 4);
    float*          states= (float*)alloc(NTOK * SS_ * 4);
    float*          chA   = (float*)alloc((size_t)B_ * NCH_ * SS_ * 4);
    float*          chB   = (float*)alloc((size_t)B_ * NCH_ * SS_ * 4);
    float*          chH   = (float*)alloc((size_t)B_ * NCH_ * SS_ * 4);
    __hip_bfloat16* Wt_mlp= (__hip_bfloat16*)alloc(3 * 512 * 512 * 2);
    __hip_bfloat16* Wt_out= (__hip_bfloat16*)alloc(256 * 512 * 2);
    __hip_bfloat16* Wt_win= (__hip_bfloat16*)alloc(512 * FEATP_ * 2);
    __hip_bfloat16* Wt_gd = (__hip_bfloat16*)alloc(64 * 512 * 2);

    k_prep_w<<<4032, 256, 0, stream>>>(mlp_w, Wout, Win, Wg, Wi, Wt_mlp, Wt_out, Wt_win, Wt_gd);
    k_token_feats<<<NTOK / 4, 256, 0, stream>>>(chars, emb_byte, hash_tables, Wq, bq, featb, hfpre);
    k_conv<<<NTOK * E_ / 256, 256, 0, stream>>>(hfpre, conv_w, conv_b, featb);
    k_win_mfma<<<dim3(NTOK / 128, 4), 256, 0, stream>>>(featb, Wt_win, b_in, hbA);
    k_gates_mfma<<<NTOK / 256, 256, 0, stream>>>(hbA, Wt_gd, bg, bi, gates, drive);
    k_chunk_ab<<<B_ * NCH_ * SS_ / 256, 256, 0, stream>>>(gates, drive, chA, chB);
    k_chunk_scan<<<1, 256, 0, stream>>>(chA, chB, chH);
    k_states<<<B_ * NCH_ * SS_ / 256, 256, 0, stream>>>(gates, drive, chH, states);
    k_wo_ln<<<NTOK / 32, 256, 0, stream>>>(states, Wo, bo, ln_g, ln_b, hbA);
    k_mlp_mfma<<<dim3(NTOK / 128, 4), 256, 0, stream>>>(hbA, Wt_mlp, mlp_b, hbB);
    k_mlp_mfma<<<dim3(NTOK / 128, 4), 256, 0, stream>>>(hbB, Wt_mlp + 262144, mlp_b + 512, hbA);
    k_mlp_mfma<<<dim3(NTOK / 128, 4), 256, 0, stream>>>(hbA, Wt_mlp + 524288, mlp_b + 1024, hbB);
    k_out_mfma<<<dim3(NTOK / 128, 2), 256, 0, stream>>>(hbB, Wt_out, bout, out);
}